// Round 6
// baseline (1016.441 us; speedup 1.0000x reference)
//
#include <hip/hip_runtime.h>
#include <hip/hip_bf16.h>
#include <cstdint>
#include <cstddef>

// ---------------------------------------------------------------------------
// RetentiveSelfAttention on MI355X (gfx950)
// B=4, N=48*48=2304, D=768, H=12, d_head=64, scaling=64^-0.5=0.125
// Pipeline: pack(bf16) -> fused QKV NT-GEMM (MFMA) -> flash attention
//           (softmax then decay-mask) -> output NT-GEMM (fp32 out)
// R6: attention: S^T = K*Q^T formulation -> P relayout for O^T = V^T*P^T is
//     pure cross-lane bpermute (no LDS at all, no lgkm drains, no barriers).
//     Decay double-buffered 2 tiles ahead (HBM ~900cyc), K reload-after-use
//     (1 tile), V early-issued; asm memory fences stop the scheduler from
//     sinking the prefetches (R5's pipeline was deleted: VGPR=56 proved it).
// ---------------------------------------------------------------------------

typedef __attribute__((ext_vector_type(8))) short short8;   // 8 bf16 = 4 VGPRs
typedef __attribute__((ext_vector_type(4))) float floatx4;  // MFMA acc

#define MFMA_BF16 __builtin_amdgcn_mfma_f32_16x16x32_bf16

constexpr int BB   = 4;     // batch
constexpr int NH   = 12;    // heads
constexpr int SEQ  = 2304;  // N
constexpr int DIM  = 768;   // embed
constexpr int MROW = BB * SEQ;   // 9216
constexpr float SCALE = 0.125f;  // 64^-0.5

static __device__ __forceinline__ unsigned short f2b(float f) {
  union { float f; unsigned u; } v; v.f = f;
  unsigned r = (v.u + 0x7fffu + ((v.u >> 16) & 1u)) >> 16;  // RNE
  return (unsigned short)r;
}

// ---------------------------------------------------------------------------
// Pack: x -> bf16; Wq|Wk*s|Wv -> bf16 fused [2304x768]; Wo -> bf16;
//       bq|bk*s|bv -> fp32 fused [2304]
// ---------------------------------------------------------------------------
constexpr int NX = MROW * DIM;      // 7,077,888
constexpr int NW = DIM * DIM;       // 589,824
constexpr int PACK_TOTAL = NX + 4 * NW + 3 * DIM;

__global__ void pack_kernel(const float* __restrict__ x,
                            const float* __restrict__ Wq, const float* __restrict__ bq,
                            const float* __restrict__ Wk, const float* __restrict__ bk,
                            const float* __restrict__ Wv, const float* __restrict__ bv,
                            const float* __restrict__ Wo,
                            unsigned short* __restrict__ xb,
                            unsigned short* __restrict__ Wqkv,
                            unsigned short* __restrict__ Wob,
                            float* __restrict__ biasqkv) {
  for (int i = blockIdx.x * blockDim.x + threadIdx.x; i < PACK_TOTAL;
       i += gridDim.x * blockDim.x) {
    if (i < NX) {
      xb[i] = f2b(x[i]);
    } else if (i < NX + NW) {
      int j = i - NX;          Wqkv[j]          = f2b(Wq[j]);
    } else if (i < NX + 2 * NW) {
      int j = i - NX - NW;     Wqkv[NW + j]     = f2b(Wk[j] * SCALE);
    } else if (i < NX + 3 * NW) {
      int j = i - NX - 2 * NW; Wqkv[2 * NW + j] = f2b(Wv[j]);
    } else if (i < NX + 4 * NW) {
      int j = i - NX - 3 * NW; Wob[j]           = f2b(Wo[j]);
    } else {
      int j = i - NX - 4 * NW;
      biasqkv[j] = (j < DIM) ? bq[j]
                 : (j < 2 * DIM) ? bk[j - DIM] * SCALE
                 : bv[j - 2 * DIM];
    }
  }
}

// ---------------------------------------------------------------------------
// NT GEMM: C[M,Nc] = A[M,K](bf16) @ B[Nc,K](bf16)^T + bias
// MODE 0: scatter to Q/K (per-head [b,h,row,64]) and V^T ([b,h,64,row]) bf16
// MODE 1: fp32 dense output [M,Nc]
// 128x128 block tile, BK=64, 4 waves (2x2), 16x16x32 MFMA, 4x4 tiles/wave.
// ---------------------------------------------------------------------------
template <int MODE>
__global__ __launch_bounds__(256)
void gemm_nt(const unsigned short* __restrict__ A,
             const unsigned short* __restrict__ Bm,
             const float* __restrict__ bias,
             int M, int Nc, int K,
             unsigned short* __restrict__ Qb,
             unsigned short* __restrict__ Kb,
             unsigned short* __restrict__ Vt,
             float* __restrict__ Out) {
  __shared__ unsigned short As[128][72];  // 64 data + 8 pad (144B stride, 16B-aligned)
  __shared__ unsigned short Bs[128][72];

  const int t    = threadIdx.x;
  const int m0   = blockIdx.x * 128;
  const int n0   = blockIdx.y * 128;
  const int w    = t >> 6;
  const int lane = t & 63, quad = lane >> 4, ln = lane & 15;
  const int wm = (w >> 1) * 64, wn = (w & 1) * 64;

  const int srow = t >> 3;          // 0..31: 8 threads x 8 bf16 per 64-wide row
  const int scol = (t & 7) * 8;     // 0,8,...,56

  floatx4 acc[4][4] = {};

  for (int k0 = 0; k0 < K; k0 += 64) {
    __syncthreads();
#pragma unroll
    for (int rr = 0; rr < 4; ++rr) {
      *(uint4*)&As[srow + rr * 32][scol] =
          *(const uint4*)&A [(size_t)(m0 + srow + rr * 32) * K + k0 + scol];
      *(uint4*)&Bs[srow + rr * 32][scol] =
          *(const uint4*)&Bm[(size_t)(n0 + srow + rr * 32) * K + k0 + scol];
    }
    __syncthreads();

#pragma unroll
    for (int s = 0; s < 2; ++s) {
      short8 af[4], bf[4];
#pragma unroll
      for (int i = 0; i < 4; ++i)
        af[i] = *(const short8*)&As[wm + i * 16 + ln][s * 32 + quad * 8];
#pragma unroll
      for (int j = 0; j < 4; ++j)
        bf[j] = *(const short8*)&Bs[wn + j * 16 + ln][s * 32 + quad * 8];
#pragma unroll
      for (int i = 0; i < 4; ++i)
#pragma unroll
        for (int j = 0; j < 4; ++j)
          acc[i][j] = MFMA_BF16(af[i], bf[j], acc[i][j], 0, 0, 0);
    }
  }

  // epilogue; C layout: col = ln, row = quad*4 + r  [measured m89/m91]
#pragma unroll
  for (int i = 0; i < 4; ++i) {
#pragma unroll
    for (int j = 0; j < 4; ++j) {
      const int n = n0 + wn + j * 16 + ln;
      const float bn = bias[n];
#pragma unroll
      for (int r = 0; r < 4; ++r) {
        const int m = m0 + wm + i * 16 + quad * 4 + r;
        const float val = acc[i][j][r] + bn;
        if (MODE == 0) {
          const int b = m / SEQ, row = m - b * SEQ;
          const int which = n / DIM, rem = n - which * DIM;
          const int h = rem >> 6, d = rem & 63;
          const size_t bh = (size_t)(b * NH + h);
          if (which == 0)      Qb[(bh * SEQ + row) * 64 + d] = f2b(val);
          else if (which == 1) Kb[(bh * SEQ + row) * 64 + d] = f2b(val);
          else                 Vt[(bh * 64 + d) * SEQ + row] = f2b(val);
        } else {
          Out[(size_t)m * Nc + n] = val;
        }
      }
    }
  }
}

// ---------------------------------------------------------------------------
// Flash attention, max-free softmax, post-softmax decay mask. NO LDS.
// grid = (144 q-tiles of 16 rows, 12 heads); block = 256 = 4 waves.
// Wave w = batch w; all 4 waves read the SAME decay rows (L1 sharing).
// S^T = K(A-op) @ Q(B-op): C-layout gives col=ln=q. P^T enters PV as the
// B-operand of O^T = V^T(A-op) @ P^T via cross-lane bpermute:
//   dest (quad,ln), key=s2*32+quad*8+j  <-  src lane ((quad&1)*2+(j>>2))*16+ln,
//   frag 2*s2+(quad>>1), reg j&3.   (2 shfl + cndmask per element)
// Prefetch: decay 2 tiles ahead (dbuf), K reload-after-use (1 tile),
// V early-issue; asm memory fences pin the load placement.
// Epilogue: den (per-lane, q=ln) reduced by 2 shfl_xor; 8B packed stores.
// ---------------------------------------------------------------------------
__global__ __launch_bounds__(256, 3)
void attn_kernel(const unsigned short* __restrict__ Qb,
                 const unsigned short* __restrict__ Kb,
                 const unsigned short* __restrict__ Vt,
                 const float* __restrict__ decay,
                 unsigned short* __restrict__ attn_b) {
  const int t = threadIdx.x;
  const int w = t >> 6;                 // batch
  const int lane = t & 63, quad = lane >> 4, ln = lane & 15;
  const int qt = blockIdx.x;
  const int h  = blockIdx.y;
  const int q0 = qt * 16;               // q-rows shared by all 4 waves

  const size_t bh = (size_t)(w * NH + h);
  const unsigned short* Qp = Qb + bh * SEQ * 64;
  const unsigned short* Kp = Kb + bh * SEQ * 64;
  const unsigned short* Vp = Vt + bh * 64 * SEQ;
  // decay row for this lane's q (= q0 + ln) — identical across the 4 waves
  const float* drow = decay + (size_t)h * SEQ * SEQ + (size_t)(q0 + ln) * SEQ;

  // Q as B-operand: B[n=ln][k=s*32+quad*8+j]
  short8 qf[2];
#pragma unroll
  for (int s = 0; s < 2; ++s)
    qf[s] = *(const short8*)&Qp[(size_t)(q0 + ln) * 64 + s * 32 + quad * 8];

  floatx4 O[4] = {};   // O^T C-frags: row=quad*4+r = d_local, col=ln = q
  float den = 0.f;     // per-lane: q = ln

  short8 kc[2][4];     // K A-frags, reload-after-use
  float4 Dbuf[2][4];   // decay double buffer: [buf][s2*2 + half]

  auto loadK = [&](int jt) {
#pragma unroll
    for (int s = 0; s < 2; ++s)
#pragma unroll
      for (int tt = 0; tt < 4; ++tt)
        kc[s][tt] = *(const short8*)&Kp[(size_t)(jt * 64 + tt * 16 + ln) * 64 + s * 32 + quad * 8];
  };
  auto loadD = [&](int jt, float4* Db) {
#pragma unroll
    for (int s2 = 0; s2 < 2; ++s2) {
      const float* dp = &drow[jt * 64 + s2 * 32 + quad * 8];
      Db[s2 * 2]     = *(const float4*)dp;
      Db[s2 * 2 + 1] = *(const float4*)(dp + 4);
    }
  };

  loadK(0);
  loadD(0, Dbuf[0]);
  loadD(1, Dbuf[1]);

  auto body = [&](int jt, float4* Dcur) {
    const int j0 = jt * 64;

    // V^T A-frags for THIS tile, issued early (used at PV, ~400+ cyc later)
    short8 vf[2][4];
#pragma unroll
    for (int s2 = 0; s2 < 2; ++s2)
#pragma unroll
      for (int dt = 0; dt < 4; ++dt)
        vf[s2][dt] = *(const short8*)&Vp[(size_t)(dt * 16 + ln) * SEQ + j0 + s2 * 32 + quad * 8];

    // S^T = K @ Q^T  (K pre-scaled by 0.125 at pack time)
    floatx4 S[4] = {};
#pragma unroll
    for (int s = 0; s < 2; ++s)
#pragma unroll
      for (int tt = 0; tt < 4; ++tt)
        S[tt] = MFMA_BF16(kc[s][tt], qf[s], S[tt], 0, 0, 0);

    // K for next tile (regs just freed by the MFMAs above)
    loadK(jt + 1 < 36 ? jt + 1 : 0);
    asm volatile("" ::: "memory");  // pin V+K load issue above the VALU wall

    // exp + den (src side: each lane's 16 values are all for q = ln)
    float E[4][4];
#pragma unroll
    for (int tt = 0; tt < 4; ++tt)
#pragma unroll
      for (int r = 0; r < 4; ++r) {
        E[tt][r] = __expf(S[tt][r]);
        den += E[tt][r];
      }

    // P^T B-frags via bpermute; multiply by decay (dest q = ln); PV MFMA
    const int src_lo = ((quad & 1) * 2) * 16 + ln;
    const int src_hi = src_lo + 16;
    const bool hiFrag = (quad >> 1) != 0;
#pragma unroll
    for (int s2 = 0; s2 < 2; ++s2) {
      const float4 d0 = Dcur[s2 * 2], d1 = Dcur[s2 * 2 + 1];
      float pv[8];
#pragma unroll
      for (int r = 0; r < 4; ++r) {
        const float aL = __shfl(E[2 * s2][r],     src_lo);
        const float bL = __shfl(E[2 * s2 + 1][r], src_lo);
        const float aH = __shfl(E[2 * s2][r],     src_hi);
        const float bH = __shfl(E[2 * s2 + 1][r], src_hi);
        pv[r]     = hiFrag ? bL : aL;
        pv[4 + r] = hiFrag ? bH : aH;
      }
      short8 pf;
      pf[0] = (short)f2b(pv[0] * d0.x); pf[1] = (short)f2b(pv[1] * d0.y);
      pf[2] = (short)f2b(pv[2] * d0.z); pf[3] = (short)f2b(pv[3] * d0.w);
      pf[4] = (short)f2b(pv[4] * d1.x); pf[5] = (short)f2b(pv[5] * d1.y);
      pf[6] = (short)f2b(pv[6] * d1.z); pf[7] = (short)f2b(pv[7] * d1.w);
#pragma unroll
      for (int dt = 0; dt < 4; ++dt)
        O[dt] = MFMA_BF16(vf[s2][dt], pf, O[dt], 0, 0, 0);
    }

    // decay for jt+2 into the buffer just consumed (~2 tiles of distance)
    loadD(jt + 2 < 36 ? jt + 2 : 0, Dcur);
    asm volatile("" ::: "memory");
  };

  for (int jt2 = 0; jt2 < 18; ++jt2) {
    body(2 * jt2,     Dbuf[0]);
    body(2 * jt2 + 1, Dbuf[1]);
  }

  // den: sum quad partials (lanes ln, 16+ln, 32+ln, 48+ln all hold q=ln)
  den += __shfl_xor(den, 16);
  den += __shfl_xor(den, 32);
  const float dinv = 1.0f / den;

  // O^T: row=quad*4+r = d_local, col=ln = q. Pack 4 bf16 -> 8B stores.
#pragma unroll
  for (int dt = 0; dt < 4; ++dt) {
    ushort4 pk;
    pk.x = f2b(O[dt][0] * dinv);
    pk.y = f2b(O[dt][1] * dinv);
    pk.z = f2b(O[dt][2] * dinv);
    pk.w = f2b(O[dt][3] * dinv);
    *(ushort4*)&attn_b[((size_t)(w * SEQ + q0 + ln)) * DIM + h * 64 + dt * 16 + quad * 4] = pk;
  }
}

// ---------------------------------------------------------------------------
extern "C" void kernel_launch(void* const* d_in, const int* in_sizes, int n_in,
                              void* d_out, int out_size, void* d_ws, size_t ws_size,
                              hipStream_t stream) {
  const float* x     = (const float*)d_in[0];
  const float* decay = (const float*)d_in[1];
  const float* Wq    = (const float*)d_in[2];
  const float* bq    = (const float*)d_in[3];
  const float* Wk    = (const float*)d_in[4];
  const float* bk    = (const float*)d_in[5];
  const float* Wv    = (const float*)d_in[6];
  const float* bv    = (const float*)d_in[7];
  const float* Wo    = (const float*)d_in[8];
  const float* bo    = (const float*)d_in[9];
  float* out = (float*)d_out;

  char* ws = (char*)d_ws;
  size_t off = 0;
  auto alloc = [&](size_t bytes) {
    void* p = ws + off;
    off += (bytes + 255) & ~(size_t)255;
    return p;
  };
  unsigned short* xb      = (unsigned short*)alloc((size_t)MROW * DIM * 2);  // 14.2 MB
  unsigned short* Wqkv    = (unsigned short*)alloc((size_t)3 * NW * 2);      //  3.5 MB
  unsigned short* Wob     = (unsigned short*)alloc((size_t)NW * 2);          //  1.2 MB
  float*          biasqkv = (float*)alloc((size_t)3 * DIM * 4);
  unsigned short* Qb      = (unsigned short*)alloc((size_t)MROW * DIM * 2);  // 14.2 MB
  unsigned short* Kb      = (unsigned short*)alloc((size_t)MROW * DIM * 2);  // 14.2 MB
  unsigned short* Vt      = (unsigned short*)alloc((size_t)MROW * DIM * 2);  // 14.2 MB
  unsigned short* attn_b  = xb;  // xb is dead after gemm<0>; alias (~61 MB total)
  (void)ws_size; (void)in_sizes; (void)n_in; (void)out_size;

  pack_kernel<<<4096, 256, 0, stream>>>(x, Wq, bq, Wk, bk, Wv, bv, Wo,
                                        xb, Wqkv, Wob, biasqkv);

  gemm_nt<0><<<dim3(MROW / 128, 2304 / 128), 256, 0, stream>>>(
      xb, Wqkv, biasqkv, MROW, 3 * DIM, DIM, Qb, Kb, Vt, nullptr);

  attn_kernel<<<dim3(SEQ / 16, NH), 256, 0, stream>>>(Qb, Kb, Vt, decay, attn_b);

  gemm_nt<1><<<dim3(MROW / 128, DIM / 128), 256, 0, stream>>>(
      attn_b, Wob, bo, MROW, DIM, DIM, nullptr, nullptr, nullptr, out);
}